// Round 2
// baseline (77.755 us; speedup 1.0000x reference)
//
#include <hip/hip_runtime.h>

// Quantum circuit sim: 12 wires, DIM=4096, 3 layers, batch=512, fp32.
// R8 = occupancy rewrite (resubmit; R1 bench was an infra failure --
// container acquire failed, no test/profile signal was produced).
// R7's "4 blocks/CU" launch_bounds was a no-op: grid = batch = 512 blocks
// on 256 CUs caps at 2 blocks/CU, so 256-thread blocks pin the CU at
// 8 waves = 2 waves/SIMD (the R5 stall-bound regime).
// R8 moves waves into the block: 512 threads (8 waves), PER=8
//   -> 2 blocks/CU x 8 waves = 16 waves/CU = 4 waves/SIMD (2x hiding).
// Wire plan per layer (i = (t<<3)|k, t 9 bits, k 3 bits):
//   wires 9-11 : k bits 2..0  -> in-register apply3 (st = 4,2,1)
//   wires 3-8  : t bits 5..0  -> ds_swizzle / shfl_xor lane exchange,
//                                no LDS buffer traffic, NO barriers
//   wires 0-2  : t bits 8..6  -> one LDS transpose: D-write -> T-read
//                                (k' = i[11:9]), apply3, T-write-back
// Wide LDS full-state passes: 10 (was 16); barriers: 9 (was ~11).
// CNOT chain folded to Gray map in gather addrs (new[i] = old[i^(i>>1)]):
//   j = Gray12((t<<3)|k) = (Gray9(t)<<3) | (Gray3(k) ^ ((t&1)<<2)).
// Final layer's CNOT perm folded into measurement weights: regs hold
// T-layout j=(k<<9)|t; logical m = invGray12(j):
//   m[11:9] = invGray3(k),  m[8:0] = invGray9(t) ^ (parity3(k)*0x1FF).
// LDS layout f(i) = 18*(i>>4)+(i&15) kept: D-write = 4x b128 full-BW,
// T-read/write b64 at 4 dwords/bank (optimal), gather ~uniform.
// Inline-asm v_pk_fma_f32/v_pk_mul_f32 complex core kept (8 VOP3P/pair).

namespace {

typedef float v2f __attribute__((ext_vector_type(2)));

constexpr int N_WIRES  = 12;
constexpr int DIM      = 1 << N_WIRES;        // 4096
constexpr int THREADS  = 512;
constexpr int PER      = 8;                   // amps per thread
constexpr int NGATES   = 36;
constexpr int PADC     = 4606;                // max f(i) = 18*255+15 = 4605

// ---- Packed complex helpers. v2f = (re, im) in a VGPR pair.
// d = u * p:
//   inst1: d.lo = p.re*u.re          d.hi = p.im*u.re
//   inst2: d.lo += p.im*(-u.im)      d.hi += p.re*u.im
__device__ __forceinline__ v2f cmul(v2f u, v2f p) {
    v2f d;
    asm("v_pk_mul_f32 %0, %1, %2 op_sel_hi:[1,0]"
        : "=v"(d) : "v"(p), "v"(u));
    asm("v_pk_fma_f32 %0, %1, %2, %0 op_sel:[1,1,0] op_sel_hi:[0,1,1] neg_lo:[0,1,0]"
        : "+v"(d) : "v"(p), "v"(u));
    return d;
}
// d += u * p
__device__ __forceinline__ void cfma(v2f& d, v2f u, v2f p) {
    asm("v_pk_fma_f32 %0, %1, %2, %0 op_sel_hi:[1,0,1]"
        : "+v"(d) : "v"(p), "v"(u));
    asm("v_pk_fma_f32 %0, %1, %2, %0 op_sel:[1,1,0] op_sel_hi:[0,1,1] neg_lo:[0,1,0]"
        : "+v"(d) : "v"(p), "v"(u));
}

// 3 in-register gates on k bits; gate gbase+gg pairs k-bit (2-gg).
__device__ __forceinline__ void apply3(v2f amp[PER], const v2f (*Um)[4], int gbase)
{
    #pragma unroll
    for (int gg = 0; gg < 3; ++gg) {
        const v2f u00 = Um[gbase + gg][0];
        const v2f u01 = Um[gbase + gg][1];
        const v2f u10 = Um[gbase + gg][2];
        const v2f u11 = Um[gbase + gg][3];
        const int st = 4 >> gg;
        #pragma unroll
        for (int k0 = 0; k0 < PER; ++k0) {
            if (k0 & st) continue;              // static under full unroll
            const int k1 = k0 | st;
            const v2f p = amp[k0], q = amp[k1];
            v2f np = cmul(u00, p); cfma(np, u01, q);
            v2f nq = cmul(u10, p); cfma(nq, u11, q);
            amp[k0] = np;
            amp[k1] = nq;
        }
    }
}

// Cross-lane xor exchange. masks 1..16: ds_swizzle within 32-lane groups
// (BitMode: offset = (xor<<10)|(or<<5)|and, and=0x1F). mask 32: shfl_xor.
template<int MASK>
__device__ __forceinline__ float shx(float v) {
    if constexpr (MASK == 32) {
        return __shfl_xor(v, 32, 64);
    } else {
        return __int_as_float(__builtin_amdgcn_ds_swizzle(
            __float_as_int(v), (MASK << 10) | 0x1F));
    }
}

// Gate on a lane bit: partner = lane ^ MASK. Lane with bit=0 computes
// n = u00*self + u01*partner; bit=1: n = u11*self + u10*partner.
template<int MASK>
__device__ __forceinline__ void shuffle_gate(v2f amp[PER], const v2f (*Um)[4],
                                             int g, int t)
{
    const v2f u00 = Um[g][0], u01 = Um[g][1], u10 = Um[g][2], u11 = Um[g][3];
    const bool hi = (t & MASK) != 0;
    const v2f ua = hi ? u11 : u00;   // multiplies self
    const v2f ub = hi ? u10 : u01;   // multiplies partner
    v2f q[PER];
    #pragma unroll
    for (int k = 0; k < PER; ++k) {
        q[k].x = shx<MASK>(amp[k].x);
        q[k].y = shx<MASK>(amp[k].y);
    }
    #pragma unroll
    for (int k = 0; k < PER; ++k) {
        v2f n = cmul(ua, amp[k]);
        cfma(n, ub, q[k]);
        amp[k] = n;
    }
}

__global__ __launch_bounds__(THREADS, 4)
void qcirc_kernel(const float* __restrict__ state,
                  const float* __restrict__ weights,
                  const float* __restrict__ head_w,
                  const float* __restrict__ head_b,
                  float* __restrict__ out)
{
    __shared__ __align__(16) v2f buf[PADC];
    __shared__ __align__(16) v2f Umat[NGATES][4];
    __shared__ float redbuf[THREADS / 64];

    const int t = threadIdx.x;                 // 9 bits
    const int b = blockIdx.x;

    // ---- 36 gate matrices. U = RZ(c)RY(b)RX(a); SU(2):
    // U = [[u00, -conj(u10)], [u10, conj(u00)]].
    if (t < NGATES) {
        const float* wp = weights + t * 3;
        float ha = 0.5f * wp[0], hb = 0.5f * wp[1], hc = 0.5f * wp[2];
        float ca = cosf(ha), sa = sinf(ha);
        float cb = cosf(hb), sb = sinf(hb);
        float ecr = cosf(hc), eci = -sinf(hc);   // e^{-i c/2}
        float t0 = cb * ca, t1 = sb * sa, t2 = sb * ca, t3 = cb * sa;
        float u00r =  ecr * t0 - eci * t1;
        float u00i =  ecr * t1 + eci * t0;
        float u10r =  ecr * t2 - eci * t3;
        float u10i = -ecr * t3 - eci * t2;
        Umat[t][0] = (v2f){ u00r,  u00i};   // u00
        Umat[t][1] = (v2f){-u10r,  u10i};   // u01 = -conj(u10)
        Umat[t][2] = (v2f){ u10r,  u10i};   // u10
        Umat[t][3] = (v2f){ u00r, -u00i};   // u11 = conj(u00)
    }

    // ---- Layout bases (f(i) = 18*(i>>4) + (i&15), v2f units).
    // D-layout: i = (t<<3)|j  -> addr = bD + j  (j = 0..7 contiguous)
    const int bD = 18 * (t >> 1) + ((t & 1) << 3);
    // T-layout: i = (k<<9)|t  -> addr = 576*k + bT
    const int bT = 18 * (t >> 4) + (t & 15);
    // Gather (CNOT Gray map): j = (Gray9(t)<<3) | (Gray3(k) ^ ((t&1)<<2))
    const int gb    = t ^ (t >> 1);                    // Gray9(t)
    const int gbase = 18 * (gb >> 1) + ((gb & 1) << 3);
    const int tx4   = (t & 1) << 2;

    // ---- Initial load, D-layout: amp[j] = state[(t<<3)|j] (32 B/lane).
    v2f amp[PER];
    {
        const float4* sp = reinterpret_cast<const float4*>(
            state + (size_t)b * DIM + (t << 3));
        float4 a0 = sp[0], a1 = sp[1];
        amp[0] = (v2f){a0.x, 0.f}; amp[1] = (v2f){a0.y, 0.f};
        amp[2] = (v2f){a0.z, 0.f}; amp[3] = (v2f){a0.w, 0.f};
        amp[4] = (v2f){a1.x, 0.f}; amp[5] = (v2f){a1.y, 0.f};
        amp[6] = (v2f){a1.z, 0.f}; amp[7] = (v2f){a1.w, 0.f};
    }
    __syncthreads();   // Umat ready

    #pragma unroll
    for (int l = 0; l < 3; ++l) {
        const int g0 = l * 12;
        if (l > 0) {
            // Gather through CNOT perm into D-layout registers.
            // k<4 : Gray3(k) in {0,1,3,2}, bit2=0 -> xor tx4 == +tx4
            // k>=4: Gray3(k) in {6,7,5,4}, bit2=1 -> xor tx4 == -tx4
            const v2f* gp = &buf[gbase + tx4];
            const v2f* gm = &buf[gbase - tx4];
            amp[0] = gp[0]; amp[1] = gp[1]; amp[2] = gp[3]; amp[3] = gp[2];
            amp[4] = gm[6]; amp[5] = gm[7]; amp[6] = gm[5]; amp[7] = gm[4];
        }

        // Wires 9,10,11: k bits 2,1,0 (in-reg).
        apply3(amp, Umat, g0 + 9);
        // Wires 3..8: i bits 8..3 = t bits 5..0 -> masks 32..1. Commuting
        // 1q gates, order within layer irrelevant. No LDS buf, no barriers.
        shuffle_gate<32>(amp, Umat, g0 + 3, t);
        shuffle_gate<16>(amp, Umat, g0 + 4, t);
        shuffle_gate< 8>(amp, Umat, g0 + 5, t);
        shuffle_gate< 4>(amp, Umat, g0 + 6, t);
        shuffle_gate< 2>(amp, Umat, g0 + 7, t);
        shuffle_gate< 1>(amp, Umat, g0 + 8, t);

        if (l > 0) __syncthreads();   // anti-dep: all gather-reads done
                                      // before any D-write below
        // D-write: 8 contiguous v2f = 4x b128, 16-B aligned, full bank BW.
        {
            float4* w = reinterpret_cast<float4*>(&buf[bD]);
            w[0] = make_float4(amp[0].x, amp[0].y, amp[1].x, amp[1].y);
            w[1] = make_float4(amp[2].x, amp[2].y, amp[3].x, amp[3].y);
            w[2] = make_float4(amp[4].x, amp[4].y, amp[5].x, amp[5].y);
            w[3] = make_float4(amp[6].x, amp[6].y, amp[7].x, amp[7].y);
        }
        __syncthreads();

        // T-read: k' = i[11:9] -> wires 0,1,2 become register bits.
        #pragma unroll
        for (int k = 0; k < PER; ++k) amp[k] = buf[bT + 576 * k];
        apply3(amp, Umat, g0 + 0);     // wires 0,1,2: k' bits 2,1,0
        if (l < 2) {
            #pragma unroll
            for (int k = 0; k < PER; ++k) buf[bT + 576 * k] = amp[k];
            __syncthreads();           // visible to next layer's gather
        }
    }

    // ---- Measurement. Regs hold pre-final-CNOT state at j=(k<<9)|t;
    // logical m = invGray12(j): m[11:9] = invGray3(k),
    // m[8:0] = invGray9(t) ^ (parity3(k) * 0x1FF).
    float hw[N_WIRES];
    #pragma unroll
    for (int w = 0; w < N_WIRES; ++w) hw[w] = head_w[w];
    int it = t ^ (t >> 1); it ^= it >> 2; it ^= it >> 4; it ^= it >> 8; // invGray9
    float chi = 0.f;                   // wires 3..11 <-> m bits 8..0
    #pragma unroll
    for (int w = 3; w < 12; ++w)
        chi += ((it >> (11 - w)) & 1) ? -hw[w] : hw[w];

    float acc = 0.f;
    #pragma unroll
    for (int k = 0; k < PER; ++k) {
        const int m3 = (k ^ (k >> 1) ^ (k >> 2)) & 7;  // invGray3(k), static
        const int p3 = __popc(k) & 1;                  // parity3(k), static
        float c = p3 ? -chi : chi;
        c += (m3 & 4) ? -hw[0] : hw[0];
        c += (m3 & 2) ? -hw[1] : hw[1];
        c += (m3 & 1) ? -hw[2] : hw[2];
        float p = amp[k].x * amp[k].x + amp[k].y * amp[k].y;
        acc += p * c;
    }

    #pragma unroll
    for (int off = 32; off > 0; off >>= 1)
        acc += __shfl_down(acc, off, 64);
    if ((t & 63) == 0) redbuf[t >> 6] = acc;
    __syncthreads();
    if (t == 0) {
        float s = 0.f;
        #pragma unroll
        for (int q = 0; q < THREADS / 64; ++q) s += redbuf[q];
        out[b] = s + head_b[0];
    }
}

} // namespace

extern "C" void kernel_launch(void* const* d_in, const int* in_sizes, int n_in,
                              void* d_out, int out_size, void* d_ws, size_t ws_size,
                              hipStream_t stream)
{
    const float* state   = (const float*)d_in[0];  // (B, 4096) fp32
    const float* weights = (const float*)d_in[1];  // (3, 12, 3) fp32
    const float* head_w  = (const float*)d_in[2];  // (1, 12) fp32
    const float* head_b  = (const float*)d_in[3];  // (1,) fp32
    float* out = (float*)d_out;                    // (B,) fp32

    const int batch = in_sizes[0] / DIM;           // 512
    qcirc_kernel<<<batch, THREADS, 0, stream>>>(state, weights, head_w, head_b, out);
}